// Round 1
// baseline (85.852 us; speedup 1.0000x reference)
//
#include <hip/hip_runtime.h>

// Forward collapse:
//   c = y[b]; k = argmax_k(logits[c,k] + gumbel[c,b,k]) (first max)
//   x[b,:] = L[c,k] @ z[b,:] + m[c,k,:]
//
// Round 19: latency/occupancy attack on the R16/R18 structure.
//  - A-fragments read DIRECTLY from global L (L2-hot, 64B-coalesced) with
//    inline fp32->bf16 cvt, same as B (z) already was. Removes the 17 KB
//    pitched LDS tile, its reg prefetch (-32 VGPR), and the store phase.
//  - y loaded FIRST so the scan's vmcnt wait isn't queued behind prefetches.
//  - __launch_bounds__(256,4): 4 blocks/CU -> all 800 blocks co-resident
//    (one scheduling round instead of two; each round pays ~4 dependent
//    cold-miss latencies after the 256 MiB harness poison flushes caches).
// Grid (100 ck, 2 jh, 4 slices) = 800 blocks, 256 thr, ~1 KB LDS.

#define N_Z 128
#define N_COMP 10
#define N_CLASSES 10
#define N_CK (N_CLASSES * N_COMP)
#define NSL 4            // sample slices
#define LIST_CAP 256

typedef __attribute__((ext_vector_type(8))) __bf16 bf16x8;
typedef __attribute__((ext_vector_type(4))) float f32x4;

__global__ __launch_bounds__(256, 4) void k_all(
    const float* __restrict__ z, const int* __restrict__ y,
    const float* __restrict__ gumbel, const float* __restrict__ m,
    const float* __restrict__ L, const float* __restrict__ logits,
    float* __restrict__ out, int bs)
{
    const int ck  = blockIdx.x;
    const int jh  = blockIdx.y;              // j range [jh*64, jh*64+64)
    const int slc = blockIdx.z;              // sample slice 0..3
    const int c   = ck / N_COMP;
    const int kk  = ck - c * N_COMP;
    const int t   = threadIdx.x;

    __shared__ int list[LIST_CAP];           // match list (~20 typical)
    __shared__ int cnt;

    if (t == 0) cnt = 0;
    __syncthreads();   // cheap: nothing in flight yet

    // ---- y loads FIRST (scan's dependency; keep vmcnt queue clean) ----
    const int ssz   = bs / NSL;              // 2048
    const int sbase = slc * ssz;
    const uint4* y4 = (const uint4*)(y + sbase);
    uint4 ya = y4[2 * t], yb = y4[2 * t + 1];

    // ---- class logits (block-uniform -> scalar loads) ----
    float lg[N_COMP];
    #pragma unroll
    for (int k = 0; k < N_COMP; ++k) lg[k] = logits[c * N_COMP + k];

    // ---- selection over this block's slice (2048 samples, 8/thread) ----
    {
        int ys[8] = {(int)ya.x, (int)ya.y, (int)ya.z, (int)ya.w,
                     (int)yb.x, (int)yb.y, (int)yb.z, (int)yb.w};
        #pragma unroll
        for (int e = 0; e < 8; ++e) {
            if (ys[e] == c) {
                int s = sbase + t * 8 + e;
                const float* g = gumbel + ((size_t)c * bs + s) * N_COMP;  // 8-B aligned
                float2 g01 = *(const float2*)(g + 0);
                float2 g23 = *(const float2*)(g + 2);
                float2 g45 = *(const float2*)(g + 4);
                float2 g67 = *(const float2*)(g + 6);
                float2 g89 = *(const float2*)(g + 8);
                float sc[N_COMP] = {
                    g01.x + lg[0], g01.y + lg[1], g23.x + lg[2], g23.y + lg[3],
                    g45.x + lg[4], g45.y + lg[5], g67.x + lg[6], g67.y + lg[7],
                    g89.x + lg[8], g89.y + lg[9] };
                float best = sc[0];
                int bi = 0;
                #pragma unroll
                for (int k = 1; k < N_COMP; ++k)
                    if (sc[k] > best) { best = sc[k]; bi = k; }  // first-max
                if (bi == kk) {
                    int p2 = atomicAdd(&cnt, 1);
                    if (p2 < LIST_CAP) list[p2] = s;
                }
            }
        }
    }
    __syncthreads();   // the only real barrier

    const int n = min(cnt, LIST_CAP);   // ~20 typical per slice
    const int ntiles = (n + 15) >> 4;

    const int wv   = t >> 6;        // wave 0..3
    const int lane = t & 63;
    const int mn   = lane & 15;     // A row / B col / D col index
    const int quad = lane >> 4;     // 0..3

    // this block's L half, row-major [64][128] fp32
    const float* Lg = L + ((size_t)ck * N_Z + jh * 64) * N_Z;

    for (int nt = wv; nt < ntiles; nt += 4) {
        const int nb = nt * 16;
        const int sidx = nb + mn;
        const int samp = list[sidx < n ? sidx : n - 1];   // clamp: dup, masked
        const float* zrow = z + (size_t)samp * N_Z;

        // ---- B-fragments direct from global (z), cvt fp32->bf16 ----
        bf16x8 bf[4];
        #pragma unroll
        for (int ks = 0; ks < 4; ++ks) {
            float4 z0 = *(const float4*)(zrow + ks * 32 + quad * 8);
            float4 z1 = *(const float4*)(zrow + ks * 32 + quad * 8 + 4);
            bf16x8 b8 = { (__bf16)z0.x, (__bf16)z0.y, (__bf16)z0.z, (__bf16)z0.w,
                          (__bf16)z1.x, (__bf16)z1.y, (__bf16)z1.z, (__bf16)z1.w };
            bf[ks] = b8;
        }

        #pragma unroll
        for (int mt = 0; mt < 4; ++mt) {
            const float* arow = Lg + (size_t)(mt * 16 + mn) * N_Z;
            f32x4 acc = {0.f, 0.f, 0.f, 0.f};
            #pragma unroll
            for (int ks = 0; ks < 4; ++ks) {
                // ---- A-fragment direct from global (L2-hot), cvt ----
                float4 a0 = *(const float4*)(arow + ks * 32 + quad * 8);
                float4 a1 = *(const float4*)(arow + ks * 32 + quad * 8 + 4);
                bf16x8 af = { (__bf16)a0.x, (__bf16)a0.y, (__bf16)a0.z, (__bf16)a0.w,
                              (__bf16)a1.x, (__bf16)a1.y, (__bf16)a1.z, (__bf16)a1.w };
                acc = __builtin_amdgcn_mfma_f32_16x16x32_bf16(af, bf[ks], acc, 0, 0, 0);
            }
            // lane owns sample col mn, j rows quad*4+0..3
            if (sidx < n) {
                int j0 = jh * 64 + mt * 16 + quad * 4;
                float4 mv = *(const float4*)(m + ck * N_Z + j0);
                float4 o;
                o.x = acc.x + mv.x;
                o.y = acc.y + mv.y;
                o.z = acc.z + mv.z;
                o.w = acc.w + mv.w;
                *(float4*)(out + (size_t)samp * N_Z + j0) = o;
            }
        }
    }
}

extern "C" void kernel_launch(void* const* d_in, const int* in_sizes, int n_in,
                              void* d_out, int out_size, void* d_ws, size_t ws_size,
                              hipStream_t stream)
{
    const float* z      = (const float*)d_in[0];
    const int*   y      = (const int*)d_in[1];
    const float* gumbel = (const float*)d_in[2];
    const float* m      = (const float*)d_in[3];
    const float* L      = (const float*)d_in[4];
    const float* logits = (const float*)d_in[5];
    float* out = (float*)d_out;

    const int bs = in_sizes[0] / N_Z;  // 8192

    k_all<<<dim3(N_CK, 2, NSL), 256, 0, stream>>>(
        z, y, gumbel, m, L, logits, out, bs);
}

// Round 2
// 80.993 us; speedup vs baseline: 1.0600x; 1.0600x over previous
//
#include <hip/hip_runtime.h>

// Forward collapse:
//   c = y[b]; k = argmax_k(logits[c,k] + gumbel[c,b,k]) (first max)
//   x[b,:] = L[c,k] @ z[b,:] + m[c,k,:]
//
// Round 20 = revert to R16/R18 structure (best measured 79.8-81.1 us)
// + ONE tweak: hoist the m-bias loads (block-uniform per quad/mt) into
// registers BEFORE the scan, so the post-barrier tail has zero cold
// global dependencies besides the unavoidable z gather.
// (R19 lesson: anything the tail reads from global is a cold HBM miss
// on the serial critical path -- the poison fill flushes L2/L3.)
//
// ONE kernel, ZERO cross-block communication. Grid (100 ck, 2 jh, 4 slices)
// = 800 blocks, 256 thr, 18.4 KB LDS. Each block independently:
//   1. prefetches its L-half (8 f4/thread) + its m-quad (4 f4) into regs,
//   2. scans its OWN 2048-sample slice: y preloaded coalesced (2 uint4/thr),
//      gumbel gathered only for y==c candidates (~205), fp32-exact argmax,
//      matches appended to LDS list (~20),
//   3. stores pitched Lsb (conflict-free), ONE barrier,
//   4. mfma_f32_16x16x32_bf16 + fp32 epilogue (m already in regs).
// Slices partition samples -> each output element written exactly once.

#define N_Z 128
#define N_COMP 10
#define N_CLASSES 10
#define N_CK (N_CLASSES * N_COMP)
#define NSL 4            // sample slices
#define LPITCH 136       // bf16 per Lsb row (272 B; 68 dw = 4 mod 32 banks)
#define LIST_CAP 256

typedef __attribute__((ext_vector_type(4))) __bf16 bf16x4;
typedef __attribute__((ext_vector_type(8))) __bf16 bf16x8;
typedef __attribute__((ext_vector_type(4))) float f32x4;

__global__ __launch_bounds__(256, 2) void k_all(
    const float* __restrict__ z, const int* __restrict__ y,
    const float* __restrict__ gumbel, const float* __restrict__ m,
    const float* __restrict__ L, const float* __restrict__ logits,
    float* __restrict__ out, int bs)
{
    const int ck  = blockIdx.x;
    const int jh  = blockIdx.y;              // j range [jh*64, jh*64+64)
    const int slc = blockIdx.z;              // sample slice 0..3
    const int c   = ck / N_COMP;
    const int kk  = ck - c * N_COMP;
    const int t   = threadIdx.x;

    __shared__ __align__(16) __bf16 Lsb[64 * LPITCH];  // 17 KB pitched rows
    __shared__ int list[LIST_CAP];                     // 1 KB
    __shared__ int cnt;

    if (t == 0) cnt = 0;
    __syncthreads();   // cheap: nothing in flight yet

    const int lane = t & 63;
    const int quad = lane >> 4;     // 0..3 (used by tail + m prefetch)

    // ---- prefetch L half into regs ----
    float4 lv[8];
    {
        const float4* Lg4 = (const float4*)(L + ((size_t)ck * N_Z + jh * 64) * N_Z);
        #pragma unroll
        for (int p = 0; p < 8; ++p) lv[p] = Lg4[p * 256 + t];
    }

    // ---- prefetch m bias (block-uniform per quad/mt) into regs ----
    float4 mvq[4];
    #pragma unroll
    for (int mt = 0; mt < 4; ++mt)
        mvq[mt] = *(const float4*)(m + ck * N_Z + jh * 64 + mt * 16 + quad * 4);

    // ---- class logits (block-uniform -> scalar loads) ----
    float lg[N_COMP];
    #pragma unroll
    for (int k = 0; k < N_COMP; ++k) lg[k] = logits[c * N_COMP + k];

    // ---- selection over this block's slice (2048 samples, 8/thread) ----
    {
        const int ssz   = bs / NSL;          // 2048
        const int sbase = slc * ssz;
        const uint4* y4 = (const uint4*)(y + sbase);
        uint4 ya = y4[2 * t], yb = y4[2 * t + 1];
        int ys[8] = {(int)ya.x, (int)ya.y, (int)ya.z, (int)ya.w,
                     (int)yb.x, (int)yb.y, (int)yb.z, (int)yb.w};
        #pragma unroll
        for (int e = 0; e < 8; ++e) {
            if (ys[e] == c) {
                int s = sbase + t * 8 + e;
                const float* g = gumbel + ((size_t)c * bs + s) * N_COMP;  // 8-B aligned
                float2 g01 = *(const float2*)(g + 0);
                float2 g23 = *(const float2*)(g + 2);
                float2 g45 = *(const float2*)(g + 4);
                float2 g67 = *(const float2*)(g + 6);
                float2 g89 = *(const float2*)(g + 8);
                float sc[N_COMP] = {
                    g01.x + lg[0], g01.y + lg[1], g23.x + lg[2], g23.y + lg[3],
                    g45.x + lg[4], g45.y + lg[5], g67.x + lg[6], g67.y + lg[7],
                    g89.x + lg[8], g89.y + lg[9] };
                float best = sc[0];
                int bi = 0;
                #pragma unroll
                for (int k = 1; k < N_COMP; ++k)
                    if (sc[k] > best) { best = sc[k]; bi = k; }  // first-max
                if (bi == kk) {
                    int p2 = atomicAdd(&cnt, 1);
                    if (p2 < LIST_CAP) list[p2] = s;
                }
            }
        }
    }

    // ---- store L half into pitched LDS (row = f>>5, col4 = f&31) ----
    #pragma unroll
    for (int p = 0; p < 8; ++p) {
        int f   = p * 256 + t;
        int row = f >> 5;
        int c4  = f & 31;
        bf16x4 b4 = { (__bf16)lv[p].x, (__bf16)lv[p].y, (__bf16)lv[p].z, (__bf16)lv[p].w };
        *(bf16x4*)&Lsb[row * LPITCH + c4 * 4] = b4;
    }
    __syncthreads();   // the only real barrier

    const int n = min(cnt, LIST_CAP);   // ~20 typical per slice
    const int ntiles = (n + 15) >> 4;

    const int wv   = t >> 6;        // wave 0..3
    const int mn   = lane & 15;     // A row / B col / D col index

    for (int nt = wv; nt < ntiles; nt += 4) {
        const int nb = nt * 16;
        const int sidx = nb + mn;
        const int samp = list[sidx < n ? sidx : n - 1];   // clamp: dup, masked
        const float* zrow = z + (size_t)samp * N_Z;

        // ---- B-fragments direct from global (L2-hot), cvt fp32->bf16 ----
        bf16x8 bf[4];
        #pragma unroll
        for (int ks = 0; ks < 4; ++ks) {
            float4 z0 = *(const float4*)(zrow + ks * 32 + quad * 8);
            float4 z1 = *(const float4*)(zrow + ks * 32 + quad * 8 + 4);
            bf16x8 b8 = { (__bf16)z0.x, (__bf16)z0.y, (__bf16)z0.z, (__bf16)z0.w,
                          (__bf16)z1.x, (__bf16)z1.y, (__bf16)z1.z, (__bf16)z1.w };
            bf[ks] = b8;
        }

        #pragma unroll
        for (int mt = 0; mt < 4; ++mt) {
            f32x4 acc = {0.f, 0.f, 0.f, 0.f};
            #pragma unroll
            for (int ks = 0; ks < 4; ++ks) {
                bf16x8 af = *(const bf16x8*)&Lsb[(mt * 16 + mn) * LPITCH + ks * 32 + quad * 8];
                acc = __builtin_amdgcn_mfma_f32_16x16x32_bf16(af, bf[ks], acc, 0, 0, 0);
            }
            // lane owns sample col mn, j rows quad*4+0..3
            if (sidx < n) {
                int j0 = jh * 64 + mt * 16 + quad * 4;
                float4 o;
                o.x = acc.x + mvq[mt].x;
                o.y = acc.y + mvq[mt].y;
                o.z = acc.z + mvq[mt].z;
                o.w = acc.w + mvq[mt].w;
                *(float4*)(out + (size_t)samp * N_Z + j0) = o;
            }
        }
    }
}

extern "C" void kernel_launch(void* const* d_in, const int* in_sizes, int n_in,
                              void* d_out, int out_size, void* d_ws, size_t ws_size,
                              hipStream_t stream)
{
    const float* z      = (const float*)d_in[0];
    const int*   y      = (const int*)d_in[1];
    const float* gumbel = (const float*)d_in[2];
    const float* m      = (const float*)d_in[3];
    const float* L      = (const float*)d_in[4];
    const float* logits = (const float*)d_in[5];
    float* out = (float*)d_out;

    const int bs = in_sizes[0] / N_Z;  // 8192

    k_all<<<dim3(N_CK, 2, NSL), 256, 0, stream>>>(
        z, y, gumbel, m, L, logits, out, bs);
}